// Round 4
// baseline (54.264 us; speedup 1.0000x reference)
//
#include <hip/hip_runtime.h>
#include <hip/hip_bf16.h>

#define BSZ   4
#define NG    15135
#define MROWS (BSZ*NG)     // 60540
#define NF    64
#define H     128
#define NCMT  1000
#define NEDGE 100000
#define HFC   256
#define NCLS  10
#define NB    64           // k2 privatized blocks
#define PSTR  5120         // partial stride (floats): [4*1000 acc | 1000 cnt | pad]
#define NHP   40           // k3a blocks (hacc partials)

typedef __attribute__((ext_vector_type(8))) short  bfrag;   // 8 bf16 = 4 VGPR
typedef __attribute__((ext_vector_type(4))) float  f32x4;

// hardware packed f32x2 -> bf16x2 (v_cvt_pk_bf16_f32)
__device__ __forceinline__ unsigned int pkbf(float a, float b) {
    union { __hip_bfloat162 h2; unsigned int u; } c;
    c.h2 = __float22bfloat162_rn(make_float2(a, b));
    return c.u;
}

// ---------------------------------------------------------------------------
// kP: pack W1^T / W2^T into MFMA-A fragment-linear bf16 layout in ws.
// W1 output channels are PERMUTED: slot (ci,m=grp*4+reg) holds global channel
//   sigma = (ci>>1)*32 + grp*8 + (ci&1)*4 + reg
// so that after GEMM1 each lane already holds its GEMM2 B-fragment channels
// (no h1 LDS round-trip in k1).  W2 k-order stays natural.
// ---------------------------------------------------------------------------
__global__ __launch_bounds__(256) void kP(const float* __restrict__ W1,
                                          const float* __restrict__ W2,
                                          unsigned int* __restrict__ wfrag_u32) {
    const int q = blockIdx.x * 256 + threadIdx.x;   // 0..12287
    const int e = 2 * q;
    float f0, f1;
    if (e < 8192) {                       // W1 frags: ct = ci*2+t (16)
        const int kk = e & 7, l = (e >> 3) & 63, ct = e >> 9;
        const int t = ct & 1, ci = ct >> 1;
        const int k = t * 32 + (l >> 4) * 8 + kk;
        const int m = l & 15;
        const int i = (ci >> 1) * 32 + (m >> 2) * 8 + (ci & 1) * 4 + (m & 3);  // sigma
        f0 = W1[k * H + i];
        f1 = W1[(k + 1) * H + i];
    } else {                              // W2 frags: ct = ci*4+t (32), natural
        const int e2 = e - 8192;
        const int kk = e2 & 7, l = (e2 >> 3) & 63, ct = e2 >> 9;
        const int t = ct & 3, ci = ct >> 2;
        const int k = t * 32 + (l >> 4) * 8 + kk;
        const int i = ci * 16 + (l & 15);
        f0 = W2[k * H + i];
        f1 = W2[(k + 1) * H + i];
    }
    wfrag_u32[q] = pkbf(f0, f1);
}

// ---------------------------------------------------------------------------
// K1: bf16-MFMA fused  h1 = relu(x@W1+b1); h2 = relu(h1@W2+b2);
//     fdot4[g][b] = sum_c h1[c]*Wfc[2c] + h2[c]*Wfc[2c+1]
// Swapped operands: C[channel][row].  4 waves x 32 rows = 128 rows/block.
// h1 never leaves registers (channel permutation in kP). LDS 48KB -> 3 blk/CU.
// ---------------------------------------------------------------------------
__global__ __launch_bounds__(256, 3) void k1_fdot(const float* __restrict__ x,
                                                  const unsigned int* __restrict__ wfrag_g,
                                                  const float* __restrict__ b1,
                                                  const float* __restrict__ b2,
                                                  const float* __restrict__ Wfc,
                                                  float* __restrict__ fdot4) {
    __shared__ unsigned int wfrag[12288];        // 48KB: w1 [0,4096) w2 [4096,12288)

    const int tid  = threadIdx.x;
    const int lane = tid & 63, wid = tid >> 6;
    const int sub  = lane & 15, grp = lane >> 4;
    const int base = blockIdx.x * 128 + wid * 32;
    const int r0 = base + sub, r1 = base + 16 + sub;
    const int rc0 = r0 < MROWS ? r0 : MROWS - 1;
    const int rc1 = r1 < MROWS ? r1 : MROWS - 1;

    // issue x loads early (hide HBM latency under the weight staging)
    float4 xr[2][4];
    #pragma unroll
    for (int t = 0; t < 2; ++t) {
        xr[0][2 * t]     = *(const float4*)&x[(size_t)rc0 * NF + t * 32 + grp * 8];
        xr[0][2 * t + 1] = *(const float4*)&x[(size_t)rc0 * NF + t * 32 + grp * 8 + 4];
        xr[1][2 * t]     = *(const float4*)&x[(size_t)rc1 * NF + t * 32 + grp * 8];
        xr[1][2 * t + 1] = *(const float4*)&x[(size_t)rc1 * NF + t * 32 + grp * 8 + 4];
    }

    {   // stage fragment weights: straight linear copy (conflict-free)
        const uint4* src = (const uint4*)wfrag_g;
        uint4* dst = (uint4*)wfrag;
        #pragma unroll
        for (int i = 0; i < 12; ++i) dst[i * 256 + tid] = src[i * 256 + tid];
    }
    __syncthreads();

    // pack x rows -> B fragments
    bfrag bx[2][2];
    #pragma unroll
    for (int s = 0; s < 2; ++s)
        #pragma unroll
        for (int t = 0; t < 2; ++t) {
            union { bfrag v; unsigned int u[4]; } pk;
            const float4 a = xr[s][2 * t], b = xr[s][2 * t + 1];
            pk.u[0] = pkbf(a.x, a.y); pk.u[1] = pkbf(a.z, a.w);
            pk.u[2] = pkbf(b.x, b.y); pk.u[3] = pkbf(b.z, b.w);
            bx[s][t] = pk.v;
        }

    const bfrag* w1f = (const bfrag*)wfrag;                 // [(ci*2+t)*64 + lane]
    const bfrag* w2f = (const bfrag*)(wfrag + 4096);        // [(ci*4+t)*64 + lane]
    float fp[2] = {0.f, 0.f};
    unsigned int p01[2][8], p23[2][8];                      // packed h1 [set][ci]

    // ---- GEMM1: permuted channels; A-frags shared across both row-sets ----
    #pragma unroll
    for (int ci = 0; ci < 8; ++ci) {
        const bfrag a0 = w1f[(ci * 2 + 0) * 64 + lane];
        const bfrag a1 = w1f[(ci * 2 + 1) * 64 + lane];
        const int c0 = (ci >> 1) * 32 + grp * 8 + (ci & 1) * 4;   // sigma base
        const float4 b1v = *(const float4*)&b1[c0];
        const float4 wfa = *(const float4*)&Wfc[2 * c0];          // we,wo pairs
        const float4 wfb = *(const float4*)&Wfc[2 * c0 + 4];
        #pragma unroll
        for (int s = 0; s < 2; ++s) {
            f32x4 c1 = {0.f, 0.f, 0.f, 0.f};
            c1 = __builtin_amdgcn_mfma_f32_16x16x32_bf16(a0, bx[s][0], c1, 0, 0, 0);
            c1 = __builtin_amdgcn_mfma_f32_16x16x32_bf16(a1, bx[s][1], c1, 0, 0, 0);
            const float h0 = fmaxf(c1[0] + b1v.x, 0.f);
            const float h1 = fmaxf(c1[1] + b1v.y, 0.f);
            const float h2 = fmaxf(c1[2] + b1v.z, 0.f);
            const float h3 = fmaxf(c1[3] + b1v.w, 0.f);
            fp[s] = fmaf(h0, wfa.x, fp[s]); fp[s] = fmaf(h1, wfa.z, fp[s]);
            fp[s] = fmaf(h2, wfb.x, fp[s]); fp[s] = fmaf(h3, wfb.z, fp[s]);
            p01[s][ci] = pkbf(h0, h1);
            p23[s][ci] = pkbf(h2, h3);
        }
    }

    // ---- GEMM2: B-fragments are lane-local (thanks to sigma) ----
    #pragma unroll
    for (int ci = 0; ci < 8; ++ci) {
        const int c0 = ci * 16 + grp * 4;                   // natural channels
        const float4 b2v = *(const float4*)&b2[c0];
        const float4 wfa = *(const float4*)&Wfc[2 * c0];
        const float4 wfb = *(const float4*)&Wfc[2 * c0 + 4];
        #pragma unroll
        for (int s = 0; s < 2; ++s) {
            f32x4 c2 = {0.f, 0.f, 0.f, 0.f};
            #pragma unroll
            for (int t = 0; t < 4; ++t) {
                union { bfrag v; unsigned int u[4]; } B;
                B.u[0] = p01[s][2 * t];     B.u[1] = p23[s][2 * t];
                B.u[2] = p01[s][2 * t + 1]; B.u[3] = p23[s][2 * t + 1];
                c2 = __builtin_amdgcn_mfma_f32_16x16x32_bf16(w2f[(ci * 4 + t) * 64 + lane], B.v, c2, 0, 0, 0);
            }
            fp[s] = fmaf(fmaxf(c2[0] + b2v.x, 0.f), wfa.y, fp[s]);
            fp[s] = fmaf(fmaxf(c2[1] + b2v.y, 0.f), wfa.w, fp[s]);
            fp[s] = fmaf(fmaxf(c2[2] + b2v.z, 0.f), wfb.y, fp[s]);
            fp[s] = fmaf(fmaxf(c2[3] + b2v.w, 0.f), wfb.w, fp[s]);
        }
    }

    // reduce over channel groups (lane bits 4,5); row = sub
    #pragma unroll
    for (int s = 0; s < 2; ++s) {
        fp[s] += __shfl_xor(fp[s], 16);
        fp[s] += __shfl_xor(fp[s], 32);
    }
    if (grp == 0) {
        if (r0 < MROWS) {
            const int b = r0 / NG, g = r0 - b * NG;
            fdot4[g * 4 + b] = fp[0];
        }
        if (r1 < MROWS) {
            const int b = r1 / NG, g = r1 - b * NG;
            fdot4[g * 4 + b] = fp[1];
        }
    }
}

// ---------------------------------------------------------------------------
// K2: privatized edge scatter.  Each block: LDS segment-sum over its edge
// slice (LDS atomics, no global atomics), then coalesced partial store.
// partial[blk][PSTR]: [v*1000+c] v<4 = batch sums ; [4000+c] = cnt (as float)
// ---------------------------------------------------------------------------
__global__ __launch_bounds__(512) void k2_scatter(const int* __restrict__ row,
                                                  const int* __restrict__ col,
                                                  const float* __restrict__ fdot4,
                                                  float* __restrict__ partial) {
    __shared__ float lacc[5 * NCMT];    // 20 KB
    const int tid = threadIdx.x;
    #pragma unroll
    for (int i = tid; i < 5 * NCMT; i += 512) lacc[i] = 0.f;
    __syncthreads();

    for (int e = blockIdx.x * 512 + tid; e < NEDGE; e += NB * 512) {
        const int r = row[e];
        const int c = col[e];
        const float4 f = *(const float4*)&fdot4[r * 4];
        atomicAdd(&lacc[c],            f.x);
        atomicAdd(&lacc[NCMT + c],     f.y);
        atomicAdd(&lacc[2 * NCMT + c], f.z);
        atomicAdd(&lacc[3 * NCMT + c], f.w);
        atomicAdd(&lacc[4 * NCMT + c], 1.f);
    }
    __syncthreads();

    float* dst = partial + (size_t)blockIdx.x * PSTR;
    #pragma unroll
    for (int i = tid; i < 5 * NCMT; i += 512) dst[i] = lacc[i];
}

// ---------------------------------------------------------------------------
// K3a: reduce partials -> scores for a 25-col chunk, then
//      hp[blk][b*256+j] = sum_{c in chunk} scores[b][c] * Wl1[c][j]
// ---------------------------------------------------------------------------
#define CCH 25
__global__ __launch_bounds__(256) void k3a_head1(const float* __restrict__ partial,
                                                 const float* __restrict__ bfc,
                                                 const float* __restrict__ Wl1,
                                                 float* __restrict__ hp) {
    __shared__ float tmp[5][CCH];
    __shared__ float sc[BSZ][CCH];
    const int c0 = blockIdx.x * CCH;
    const int t = threadIdx.x;

    if (t < 5 * CCH) {
        const int v = t / CCH, cc = t % CCH;
        float s = 0.f;
        #pragma unroll 8
        for (int blk = 0; blk < NB; ++blk)
            s += partial[(size_t)blk * PSTR + v * NCMT + c0 + cc];
        tmp[v][cc] = s;
    }
    __syncthreads();
    if (t < BSZ * CCH) {
        const int b = t / CCH, cc = t % CCH;
        sc[b][cc] = tmp[b][cc] / fmaxf(tmp[4][cc], 1.f) + bfc[0];
    }
    __syncthreads();

    float p0 = 0.f, p1 = 0.f, p2 = 0.f, p3 = 0.f;
    #pragma unroll
    for (int cc = 0; cc < CCH; ++cc) {
        const float wv = Wl1[(size_t)(c0 + cc) * HFC + t];
        p0 = fmaf(sc[0][cc], wv, p0);
        p1 = fmaf(sc[1][cc], wv, p1);
        p2 = fmaf(sc[2][cc], wv, p2);
        p3 = fmaf(sc[3][cc], wv, p3);
    }
    float* dst = hp + (size_t)blockIdx.x * (BSZ * HFC);
    dst[0 * HFC + t] = p0;
    dst[1 * HFC + t] = p1;
    dst[2 * HFC + t] = p2;
    dst[3 * HFC + t] = p3;
}

// ---------------------------------------------------------------------------
// K3b: hacc = sum(hp) + bl1; logits = relu(hacc) @ Wl2 + bl2;
//      out = log_softmax(logits)
// ---------------------------------------------------------------------------
__global__ __launch_bounds__(256) void k3b_head2(const float* __restrict__ hp,
                                                 const float* __restrict__ bl1,
                                                 const float* __restrict__ Wl2,
                                                 const float* __restrict__ bl2,
                                                 float* __restrict__ out) {
    __shared__ float hrelu[BSZ][HFC];
    __shared__ float lg[BSZ][NCLS];
    const int t = threadIdx.x;

    #pragma unroll
    for (int q = 0; q < BSZ; ++q) {       // j = q*256+t : b = q, jj = t
        float s = 0.f;
        #pragma unroll 8
        for (int blk = 0; blk < NHP; ++blk)
            s += hp[(size_t)blk * (BSZ * HFC) + q * HFC + t];
        hrelu[q][t] = fmaxf(s + bl1[t], 0.f);
    }
    __syncthreads();

    if (t < BSZ * NCLS) {
        const int b = t / NCLS, k = t % NCLS;
        float a = bl2[k];
        #pragma unroll 4
        for (int j = 0; j < HFC; ++j)
            a = fmaf(hrelu[b][j], Wl2[j * NCLS + k], a);
        lg[b][k] = a;
    }
    __syncthreads();
    if (t < BSZ * NCLS) {
        const int b = t / NCLS, k = t % NCLS;
        float m = lg[b][0];
        #pragma unroll
        for (int k2 = 1; k2 < NCLS; ++k2) m = fmaxf(m, lg[b][k2]);
        float s = 0.f;
        #pragma unroll
        for (int k2 = 0; k2 < NCLS; ++k2) s += expf(lg[b][k2] - m);
        out[b * NCLS + k] = lg[b][k] - m - logf(s);
    }
}

// ---------------------------------------------------------------------------
extern "C" void kernel_launch(void* const* d_in, const int* in_sizes, int n_in,
                              void* d_out, int out_size, void* d_ws, size_t ws_size,
                              hipStream_t stream) {
    const float* x   = (const float*)d_in[0];
    // d_in[1] = batch (unused)
    const int*   row = (const int*)d_in[2];
    const int*   col = (const int*)d_in[3];
    const float* W1  = (const float*)d_in[4];
    const float* b1  = (const float*)d_in[5];
    const float* W2  = (const float*)d_in[6];
    const float* b2  = (const float*)d_in[7];
    const float* Wfc = (const float*)d_in[8];
    const float* bfc = (const float*)d_in[9];
    const float* Wl1 = (const float*)d_in[10];
    const float* bl1 = (const float*)d_in[11];
    const float* Wl2 = (const float*)d_in[12];
    const float* bl2 = (const float*)d_in[13];

    float* ws      = (float*)d_ws;
    float* fdot4   = ws;                                   // 60544 floats
    float* partial = ws + 60544;                           // NB*PSTR = 327680
    float* hp      = ws + 388224;                          // NHP*1024 = 40960
    unsigned int* wfrag = (unsigned int*)(ws + 429184);    // 12288 u32

    kP<<<48, 256, 0, stream>>>(W1, W2, wfrag);
    k1_fdot<<<(MROWS + 127) / 128, 256, 0, stream>>>(x, wfrag, b1, b2, Wfc, fdot4);
    k2_scatter<<<NB, 512, 0, stream>>>(row, col, fdot4, partial);
    k3a_head1<<<NCMT / CCH, 256, 0, stream>>>(partial, bfc, Wl1, hp);
    k3b_head2<<<1, 256, 0, stream>>>(hp, bl1, Wl2, bl2, (float*)d_out);
}